// Round 14
// baseline (231.891 us; speedup 1.0000x reference)
//
#include <hip/hip_runtime.h>
#include <math.h>

#define II 2048
#define BB 256
#define JJ 10
#define ICH 8             // i's per block
#define ICHUNKS (II/ICH)  // 256
#define BBLK 32           // b's per block (4 waves x 8)
#define NBW 8             // b's per wave
#define SJE (BB*JJ*16)    // 40960

typedef __attribute__((address_space(3))) unsigned lds_u32;
typedef __attribute__((address_space(1))) const unsigned glb_u32;
typedef float v2f __attribute__((ext_vector_type(2)));

__device__ __forceinline__ void gload16(const float* g, float* l) {
  __builtin_amdgcn_global_load_lds((glb_u32*)g, (lds_u32*)l, 16, 0, 0);
}
__device__ __forceinline__ v2f mkv2(float a, float b) { v2f r; r.x = a; r.y = b; return r; }

// DPP row (16-lane) rotate: VALU-pipe cross-lane, no LDS traffic.
template<int N>
__device__ __forceinline__ float rrot16(float v) {
  const int i = __float_as_int(v);
  return __int_as_float(__builtin_amdgcn_update_dpp(i, i, 0x120 + N, 0xF, 0xF, false));
}
__device__ __forceinline__ float rsum16(float v) {
  v += rrot16<8>(v); v += rrot16<4>(v); v += rrot16<2>(v); v += rrot16<1>(v);
  return v;
}
__device__ __forceinline__ float xor16swz(float v) {  // lane ^ 16 (within 32-halves)
  return __int_as_float(__builtin_amdgcn_ds_swizzle(__float_as_int(v), 0x401F));
}

// BARRIER-FREE main loop (round-13) with ICH=8 -> 2048 blocks (8/CU of work).
// Staging totals are block-shape invariant here, so the split is free.
// Each lane loads its own W slice (8 x dwordx4, wave-coalesced, L2-resident
// per XCD) into VGPRs; LDS holds only the x tile + PASS2 c_tile; only one
// barrier after the x prologue (+1 before the PASS2 epilogue).
// ic remap pairs (2k,2k+1) on one XCD -> c 64B sectors stay XCD-local.
// PASS0 accumulates v2f pairs (c==0.1 deferred to finish).
template<int PASS, bool ATOMIC>
__global__ __launch_bounds__(256, 1)
void routing_pass(const float* __restrict__ x, const float* __restrict__ W,
                  const float* __restrict__ o_eff, float* __restrict__ sdst,
                  float* __restrict__ out) {
  __shared__ __align__(16) float x_lds[BBLK * ICH * 8];           // 8 KB
  __shared__ _Float16 c_tile[(PASS == 2) ? (BBLK * JJ * 10) : 4]; // 6.25 KB

  const int t = threadIdx.x;
  const int wid = t >> 6;
  const int lane = t & 63;
  const int eg = lane >> 4;            // e-group 0..3 (e = eg*4+q)
  const int j = lane & 15;             // capsule slot, valid < 10
  const int jv = (j < JJ);
  const int jr = jv ? j : 0;           // in-bounds row (junk for pad lanes)
  // paired-XCD remap: ids id and id+8 -> i-chunks 2k and 2k+1 (same XCD)
  const int idx_ = blockIdx.x;
  const int ic = (idx_ & ~15) | ((idx_ & 7) << 1) | ((idx_ >> 3) & 1);
  const int b0 = blockIdx.y * BBLK;    // b-tile
  const int bw = __builtin_amdgcn_readfirstlane(b0 + wid * NBW);
  const int i0 = ic * ICH;

  // per-lane W base: row jr, i0, eg-quarter of the 128-float (e,d) row
  const float* wbase = W + ((size_t)jr * II + i0) * 128 + eg * 32;

  float4 o4[NBW];
  if (PASS > 0) {
#pragma unroll
    for (int nb = 0; nb < NBW; ++nb)
      o4[nb] = *reinterpret_cast<const float4*>(
          o_eff + ((size_t)(bw + nb) * JJ + jr) * 16 + eg * 4);
  }

  float4 acc4[NBW];                      // PASS1/2 accumulator
  v2f accv[NBW][4];                      // PASS0 accumulator (pair form)
#pragma unroll
  for (int nb = 0; nb < NBW; ++nb) {
    acc4[nb] = make_float4(0.f, 0.f, 0.f, 0.f);
#pragma unroll
    for (int q = 0; q < 4; ++q) accv[nb][q] = mkv2(0.f, 0.f);
  }

  // one-shot x stage: 512 f4 slots (32 b x 8 i x 32 B), lane-linear dest
#pragma unroll
  for (int k = 0; k < 2; ++k) {
    const int s = k * 256 + t;
    const int bl = s >> 4, rem = s & 15, il = rem >> 1, h = rem & 1;
    const float* src = x + ((size_t)(b0 + bl) * II + i0 + il) * 8 + h * 4;
    gload16(src, &x_lds[(k * 256 + wid * 64) * 4]);
  }
  __syncthreads();   // the ONLY main-path barrier

#pragma unroll 1
  for (int il = 0; il < ICH; ++il) {
    const float* wp = wbase + il * 128;
    float4 wv[8];
#pragma unroll
    for (int r = 0; r < 8; ++r)
      wv[r] = *reinterpret_cast<const float4*>(wp + r * 4);

#pragma unroll
    for (int nb = 0; nb < NBW; ++nb) {
      const float* xp = &x_lds[((wid * NBW + nb) * ICH + il) * 8]; // broadcast
      const float4 xa = *reinterpret_cast<const float4*>(xp);
      const float4 xb = *reinterpret_cast<const float4*>(xp + 4);
      if (PASS == 0) {
        // c==0.1 distributes: accumulate pairs across (i,d); no per-i finish
#pragma unroll
        for (int q = 0; q < 4; ++q) {
          accv[nb][q] = __builtin_elementwise_fma(mkv2(wv[2*q].x, wv[2*q].y),
                                                  mkv2(xa.x, xa.y), accv[nb][q]);
          accv[nb][q] = __builtin_elementwise_fma(mkv2(wv[2*q].z, wv[2*q].w),
                                                  mkv2(xa.z, xa.w), accv[nb][q]);
          accv[nb][q] = __builtin_elementwise_fma(mkv2(wv[2*q+1].x, wv[2*q+1].y),
                                                  mkv2(xb.x, xb.y), accv[nb][q]);
          accv[nb][q] = __builtin_elementwise_fma(mkv2(wv[2*q+1].z, wv[2*q+1].w),
                                                  mkv2(xb.z, xb.w), accv[nb][q]);
        }
      } else {
#define DOT8(q, dst)                                                        \
      v2f dv##q = mkv2(wv[2*(q)].x, wv[2*(q)].y) * mkv2(xa.x, xa.y);        \
      dv##q = __builtin_elementwise_fma(mkv2(wv[2*(q)].z, wv[2*(q)].w),     \
                                        mkv2(xa.z, xa.w), dv##q);           \
      dv##q = __builtin_elementwise_fma(mkv2(wv[2*(q)+1].x, wv[2*(q)+1].y), \
                                        mkv2(xb.x, xb.y), dv##q);           \
      dv##q = __builtin_elementwise_fma(mkv2(wv[2*(q)+1].z, wv[2*(q)+1].w), \
                                        mkv2(xb.z, xb.w), dv##q);           \
      const float dst = dv##q.x + dv##q.y;
      DOT8(0, u0) DOT8(1, u1) DOT8(2, u2) DOT8(3, u3)
#undef DOT8
        float lp = o4[nb].x * u0;
        lp = fmaf(o4[nb].y, u1, lp);
        lp = fmaf(o4[nb].z, u2, lp);
        lp = fmaf(o4[nb].w, u3, lp);
        lp += xor16swz(lp);                       // reduce over 4 e-groups
        lp += __shfl_xor(lp, 32);
        // no max-subtraction: |logit| bounded (~20), fp32 exp safe
        const float pp = jv ? __expf(lp) : 0.f;
        const float su = rsum16(pp);              // DPP, VALU pipe
        const float c = pp * __builtin_amdgcn_rcpf(su);
        acc4[nb].x = fmaf(c, u0, acc4[nb].x);
        acc4[nb].y = fmaf(c, u1, acc4[nb].y);
        acc4[nb].z = fmaf(c, u2, acc4[nb].z);
        acc4[nb].w = fmaf(c, u3, acc4[nb].w);
        if (PASS == 2) {
          if (eg == 0 && jv)
            c_tile[((wid * NBW + nb) * JJ + j) * 10 + il] = (_Float16)c;
        }
      }
    }
  }

  if (PASS == 0) {
#pragma unroll
    for (int nb = 0; nb < NBW; ++nb) {
      acc4[nb].x = accv[nb][0].x + accv[nb][0].y;
      acc4[nb].y = accv[nb][1].x + accv[nb][1].y;
      acc4[nb].z = accv[nb][2].x + accv[nb][2].y;
      acc4[nb].w = accv[nb][3].x + accv[nb][3].y;
    }
  }

  if (PASS == 2) {
    __syncthreads();
    // coalesced c write: 320 rows x 8 i-floats (32 B contiguous per row)
    for (int s = t; s < BBLK * JJ * ICH; s += 256) {
      const int row = s >> 3, col = s & 7;
      const int bb = row / 10, jj = row - bb * 10;
      out[((size_t)(b0 + bb) * JJ + jj) * 2064 + 16 + i0 + col] =
          (float)c_tile[row * 10 + col];
    }
  }

  if (jv) {
#pragma unroll
    for (int nb = 0; nb < NBW; ++nb) {
      if (ATOMIC) {
        float* sp = sdst + ((size_t)(bw + nb) * JJ + j) * 16 + eg * 4;
        atomicAdd(&sp[0], acc4[nb].x);
        atomicAdd(&sp[1], acc4[nb].y);
        atomicAdd(&sp[2], acc4[nb].z);
        atomicAdd(&sp[3], acc4[nb].w);
      } else {
        float* sp = sdst + (size_t)ic * SJE +
                    ((size_t)(bw + nb) * JJ + j) * 16 + eg * 4;
        *reinterpret_cast<float4*>(sp) = acc4[nb];
      }
    }
  }
}

// fused: reduce over 256 i-chunk partials + squash + output/o_eff update
__global__ __launch_bounds__(256)
void finish_pass(const float* __restrict__ part, float* __restrict__ o_eff,
                 float* __restrict__ out, int pass) {
  const int idx = blockIdx.x * 256 + threadIdx.x;   // < 40960; 16 lanes = one (b,j)
  float a = 0.f;
#pragma unroll 8
  for (int k = 0; k < ICHUNKS; ++k) a += part[(size_t)k * SJE + idx];
  if (pass == 0) a *= 0.1f;                         // PASS0 defers c==0.1 scale
  const float s2 = rsum16(a * a);
  const float scale = s2 / ((1.f + s2) * sqrtf(s2 + 1e-7f));
  const float v = scale * a;
  if (pass == 0) o_eff[idx] = v;
  else if (pass == 1) o_eff[idx] += v;
  else out[(size_t)(idx >> 4) * 2064 + (idx & 15)] = v;
}

__global__ __launch_bounds__(256)
void squash_update(const float* __restrict__ s, float* __restrict__ o_eff,
                   float* __restrict__ out, int pass) {
  const int idx = blockIdx.x * blockDim.x + threadIdx.x;
  if (idx >= BB * JJ) return;
  const float* sp = s + (size_t)idx * 16;
  const float pre = (pass == 0) ? 0.1f : 1.f;   // PASS0 raw sums -> apply c==0.1
  float v[16];
  float s2 = 0.f;
#pragma unroll
  for (int e = 0; e < 16; ++e) { v[e] = pre * sp[e]; s2 = fmaf(v[e], v[e], s2); }
  const float scale = s2 / ((1.f + s2) * sqrtf(s2 + 1e-7f));
  if (pass == 0) {
    float* op = o_eff + (size_t)idx * 16;
#pragma unroll
    for (int e = 0; e < 16; ++e) op[e] = scale * v[e];
  } else if (pass == 1) {
    float* op = o_eff + (size_t)idx * 16;
#pragma unroll
    for (int e = 0; e < 16; ++e) op[e] += scale * v[e];
  } else {
    float* dst = out + (size_t)idx * 2064;
#pragma unroll
    for (int e = 0; e < 16; ++e) dst[e] = scale * v[e];
  }
}

extern "C" void kernel_launch(void* const* d_in, const int* in_sizes, int n_in,
                              void* d_out, int out_size, void* d_ws, size_t ws_size,
                              hipStream_t stream) {
  const float* x = (const float*)d_in[0];   // [256,2048,8]
  const float* W = (const float*)d_in[1];   // [10,2048,16,8]
  float* out = (float*)d_out;               // [256,10,2064]
  float* ws = (float*)d_ws;

  const dim3 grid(ICHUNKS, BB / BBLK);      // (256, 8) = 2048 blocks
  const size_t need = ((size_t)ICHUNKS * SJE + SJE) * sizeof(float); // ~42.1 MB

  if (ws_size >= need) {
    float* part = ws;
    float* oe   = ws + (size_t)ICHUNKS * SJE;
    routing_pass<0, false><<<grid, 256, 0, stream>>>(x, W, nullptr, part, nullptr);
    finish_pass<<<SJE / 256, 256, 0, stream>>>(part, oe, out, 0);
    routing_pass<1, false><<<grid, 256, 0, stream>>>(x, W, oe, part, nullptr);
    finish_pass<<<SJE / 256, 256, 0, stream>>>(part, oe, out, 1);
    routing_pass<2, false><<<grid, 256, 0, stream>>>(x, W, oe, part, out);
    finish_pass<<<SJE / 256, 256, 0, stream>>>(part, oe, out, 2);
  } else {
    // atomic fallback: PASS0 accumulates raw sums; 0.1 applied in squash_update
    float* s0 = ws;
    float* s1 = ws + SJE;
    float* s2 = ws + 2 * SJE;
    float* oe = ws + 3 * SJE;
    hipMemsetAsync(ws, 0, (size_t)4 * SJE * sizeof(float), stream);
    routing_pass<0, true><<<grid, 256, 0, stream>>>(x, W, nullptr, s0, nullptr);
    squash_update<<<10, 256, 0, stream>>>(s0, oe, out, 0);
    routing_pass<1, true><<<grid, 256, 0, stream>>>(x, W, oe, s1, nullptr);
    squash_update<<<10, 256, 0, stream>>>(s1, oe, out, 1);
    routing_pass<2, true><<<grid, 256, 0, stream>>>(x, W, oe, s2, out);
    squash_update<<<10, 256, 0, stream>>>(s2, oe, out, 2);
  }
}

// Round 15
// 180.125 us; speedup vs baseline: 1.2874x; 1.2874x over previous
//
#include <hip/hip_runtime.h>
#include <math.h>

#define II 2048
#define BB 256
#define JJ 10
#define ICH 16            // i's per block (PASS1/2)
#define ICHUNKS (II/ICH)  // 128
#define BBLK 32           // b's per block (4 waves x 8)
#define NBW 8             // b's per wave
#define SJE (BB*JJ*16)    // 40960

typedef __attribute__((address_space(3))) unsigned lds_u32;
typedef __attribute__((address_space(1))) const unsigned glb_u32;
typedef float v2f __attribute__((ext_vector_type(2)));
typedef __attribute__((ext_vector_type(8))) short bf16x8;
typedef __attribute__((ext_vector_type(4))) float f32x4;

__device__ __forceinline__ void gload16(const float* g, float* l) {
  __builtin_amdgcn_global_load_lds((glb_u32*)g, (lds_u32*)l, 16, 0, 0);
}
__device__ __forceinline__ v2f mkv2(float a, float b) { v2f r; r.x = a; r.y = b; return r; }

// DPP row (16-lane) rotate: VALU-pipe cross-lane, no LDS traffic.
template<int N>
__device__ __forceinline__ float rrot16(float v) {
  const int i = __float_as_int(v);
  return __int_as_float(__builtin_amdgcn_update_dpp(i, i, 0x120 + N, 0xF, 0xF, false));
}
__device__ __forceinline__ float rsum16(float v) {
  v += rrot16<8>(v); v += rrot16<4>(v); v += rrot16<2>(v); v += rrot16<1>(v);
  return v;
}
__device__ __forceinline__ float xor16swz(float v) {  // lane ^ 16 (within 32-halves)
  return __int_as_float(__builtin_amdgcn_ds_swizzle(__float_as_int(v), 0x401F));
}

// ---------------- PASS0 as bf16 MFMA GEMM ----------------
// s0[b, (j,e)] = sum_{(i,d)} x[b,(i,d)] * W[j,i,e,d]   (c==0.1 deferred)
// K = I*8; k-step 32 = 4 i's. A frag: lane -> row b = l&15, k = (l>>4)*8..+7
// (one full i-row of 8 d's, 32 B contiguous). B frag: lane -> col (j,e) with
// e = l&15, same k (W[j,i,e,0..7], 32 B contiguous). C: row (l>>4)*4+r, col l&15.
__device__ __forceinline__ unsigned cvt2(float lo, float hi) {  // RNE pack
  unsigned a = __float_as_uint(lo), b = __float_as_uint(hi);
  a = (a + 0x7fffu + ((a >> 16) & 1u)) >> 16;
  b = (b + 0x7fffu + ((b >> 16) & 1u)) >> 16;
  return a | (b << 16);
}
__device__ __forceinline__ bf16x8 cvt8(const float* p) {
  union { bf16x8 v; unsigned u[4]; } r;
  const float4 A = *reinterpret_cast<const float4*>(p);
  const float4 B = *reinterpret_cast<const float4*>(p + 4);
  r.u[0] = cvt2(A.x, A.y); r.u[1] = cvt2(A.z, A.w);
  r.u[2] = cvt2(B.x, B.y); r.u[3] = cvt2(B.z, B.w);
  return r.v;
}

__global__ __launch_bounds__(256)
void pass0_mfma(const float* __restrict__ x, const float* __restrict__ W,
                float* __restrict__ part) {
  const int t = threadIdx.x, wid = t >> 6, lane = t & 63;
  const int lg = lane >> 4, lm = lane & 15;
  const int chunk = blockIdx.x * 4 + wid;      // 0..127 (i-chunk of 16)
  const int mb = blockIdx.y * 16;              // b-tile base
  f32x4 acc0 = {0,0,0,0}, acc1 = {0,0,0,0}, acc2 = {0,0,0,0}, acc3 = {0,0,0,0};
  f32x4 acc4_ = {0,0,0,0}, acc5 = {0,0,0,0}, acc6 = {0,0,0,0}, acc7 = {0,0,0,0};
  f32x4 acc8 = {0,0,0,0}, acc9 = {0,0,0,0};
  const int ibase = chunk * 16;
#pragma unroll
  for (int ks = 0; ks < 4; ++ks) {
    const int i = ibase + ks * 4 + lg;
    const bf16x8 a = cvt8(x + ((size_t)(mb + lm) * II + i) * 8);
#define MM(J, ACC)                                                        \
    {                                                                     \
      const bf16x8 bv = cvt8(W + (((size_t)(J) * II + i) * 16 + lm) * 8); \
      ACC = __builtin_amdgcn_mfma_f32_16x16x32_bf16(a, bv, ACC, 0, 0, 0); \
    }
    MM(0, acc0) MM(1, acc1) MM(2, acc2) MM(3, acc3) MM(4, acc4_)
    MM(5, acc5) MM(6, acc6) MM(7, acc7) MM(8, acc8) MM(9, acc9)
#undef MM
  }
  float* base = part + (size_t)chunk * SJE;
#define ST(J, ACC)                                                        \
  {                                                                       \
    _Pragma("unroll")                                                     \
    for (int r = 0; r < 4; ++r)                                           \
      base[((size_t)(mb + lg * 4 + r) * JJ + (J)) * 16 + lm] = ACC[r];    \
  }
  ST(0, acc0) ST(1, acc1) ST(2, acc2) ST(3, acc3) ST(4, acc4_)
  ST(5, acc5) ST(6, acc6) ST(7, acc7) ST(8, acc8) ST(9, acc9)
#undef ST
}

// ---------------- PASS1/2: round-13 barrier-free structure ----------------
template<int PASS, bool ATOMIC>
__global__ __launch_bounds__(256, 1)
void routing_pass(const float* __restrict__ x, const float* __restrict__ W,
                  const float* __restrict__ o_eff, float* __restrict__ sdst,
                  float* __restrict__ out) {
  __shared__ __align__(16) float x_lds[BBLK * ICH * 8];           // 16 KB
  __shared__ _Float16 c_tile[(PASS == 2) ? (BBLK * JJ * 18) : 4]; // 11.25 KB

  const int t = threadIdx.x;
  const int wid = t >> 6;
  const int lane = t & 63;
  const int eg = lane >> 4;            // e-group 0..3 (e = eg*4+q)
  const int j = lane & 15;             // capsule slot, valid < 10
  const int jv = (j < JJ);
  const int jr = jv ? j : 0;           // in-bounds row (junk for pad lanes)
  const int ic = blockIdx.x;           // i-chunk (fast dim -> XCD = ic%8)
  const int b0 = blockIdx.y * BBLK;    // b-tile
  const int bw = __builtin_amdgcn_readfirstlane(b0 + wid * NBW);
  const int i0 = ic * ICH;

  const float* wbase = W + ((size_t)jr * II + i0) * 128 + eg * 32;

  float4 o4[NBW];
  if (PASS > 0) {
#pragma unroll
    for (int nb = 0; nb < NBW; ++nb)
      o4[nb] = *reinterpret_cast<const float4*>(
          o_eff + ((size_t)(bw + nb) * JJ + jr) * 16 + eg * 4);
  }

  float4 acc4[NBW];
  v2f accv[NBW][4];
#pragma unroll
  for (int nb = 0; nb < NBW; ++nb) {
    acc4[nb] = make_float4(0.f, 0.f, 0.f, 0.f);
#pragma unroll
    for (int q = 0; q < 4; ++q) accv[nb][q] = mkv2(0.f, 0.f);
  }

#pragma unroll
  for (int k = 0; k < 4; ++k) {
    const int s = k * 256 + t;
    const int bl = s >> 5, rem = s & 31, il = rem >> 1, h = rem & 1;
    const float* src = x + ((size_t)(b0 + bl) * II + i0 + il) * 8 + h * 4;
    gload16(src, &x_lds[(k * 256 + wid * 64) * 4]);
  }
  __syncthreads();   // the ONLY main-path barrier

#pragma unroll 1
  for (int il = 0; il < ICH; ++il) {
    const float* wp = wbase + il * 128;
    float4 wv[8];
#pragma unroll
    for (int r = 0; r < 8; ++r)
      wv[r] = *reinterpret_cast<const float4*>(wp + r * 4);

#pragma unroll
    for (int nb = 0; nb < NBW; ++nb) {
      const float* xp = &x_lds[((wid * NBW + nb) * ICH + il) * 8];
      const float4 xa = *reinterpret_cast<const float4*>(xp);
      const float4 xb = *reinterpret_cast<const float4*>(xp + 4);
      if (PASS == 0) {
#pragma unroll
        for (int q = 0; q < 4; ++q) {
          accv[nb][q] = __builtin_elementwise_fma(mkv2(wv[2*q].x, wv[2*q].y),
                                                  mkv2(xa.x, xa.y), accv[nb][q]);
          accv[nb][q] = __builtin_elementwise_fma(mkv2(wv[2*q].z, wv[2*q].w),
                                                  mkv2(xa.z, xa.w), accv[nb][q]);
          accv[nb][q] = __builtin_elementwise_fma(mkv2(wv[2*q+1].x, wv[2*q+1].y),
                                                  mkv2(xb.x, xb.y), accv[nb][q]);
          accv[nb][q] = __builtin_elementwise_fma(mkv2(wv[2*q+1].z, wv[2*q+1].w),
                                                  mkv2(xb.z, xb.w), accv[nb][q]);
        }
      } else {
#define DOT8(q, dst)                                                        \
      v2f dv##q = mkv2(wv[2*(q)].x, wv[2*(q)].y) * mkv2(xa.x, xa.y);        \
      dv##q = __builtin_elementwise_fma(mkv2(wv[2*(q)].z, wv[2*(q)].w),     \
                                        mkv2(xa.z, xa.w), dv##q);           \
      dv##q = __builtin_elementwise_fma(mkv2(wv[2*(q)+1].x, wv[2*(q)+1].y), \
                                        mkv2(xb.x, xb.y), dv##q);           \
      dv##q = __builtin_elementwise_fma(mkv2(wv[2*(q)+1].z, wv[2*(q)+1].w), \
                                        mkv2(xb.z, xb.w), dv##q);           \
      const float dst = dv##q.x + dv##q.y;
      DOT8(0, u0) DOT8(1, u1) DOT8(2, u2) DOT8(3, u3)
#undef DOT8
        float lp = o4[nb].x * u0;
        lp = fmaf(o4[nb].y, u1, lp);
        lp = fmaf(o4[nb].z, u2, lp);
        lp = fmaf(o4[nb].w, u3, lp);
        lp += xor16swz(lp);                       // reduce over 4 e-groups
        lp += __shfl_xor(lp, 32);
        const float pp = jv ? __expf(lp) : 0.f;   // no max-sub (logits bounded)
        const float su = rsum16(pp);
        const float c = pp * __builtin_amdgcn_rcpf(su);
        acc4[nb].x = fmaf(c, u0, acc4[nb].x);
        acc4[nb].y = fmaf(c, u1, acc4[nb].y);
        acc4[nb].z = fmaf(c, u2, acc4[nb].z);
        acc4[nb].w = fmaf(c, u3, acc4[nb].w);
        if (PASS == 2) {
          if (eg == 0 && jv)
            c_tile[((wid * NBW + nb) * JJ + j) * 18 + il] = (_Float16)c;
        }
      }
    }
  }

  if (PASS == 0) {
#pragma unroll
    for (int nb = 0; nb < NBW; ++nb) {
      acc4[nb].x = accv[nb][0].x + accv[nb][0].y;
      acc4[nb].y = accv[nb][1].x + accv[nb][1].y;
      acc4[nb].z = accv[nb][2].x + accv[nb][2].y;
      acc4[nb].w = accv[nb][3].x + accv[nb][3].y;
    }
  }

  if (PASS == 2) {
    __syncthreads();
    for (int s = t; s < BBLK * JJ * ICH; s += 256) {
      const int row = s >> 4, col = s & 15;
      const int bb = row / 10, jj = row - bb * 10;
      out[((size_t)(b0 + bb) * JJ + jj) * 2064 + 16 + i0 + col] =
          (float)c_tile[row * 18 + col];
    }
  }

  if (jv) {
#pragma unroll
    for (int nb = 0; nb < NBW; ++nb) {
      if (ATOMIC) {
        float* sp = sdst + ((size_t)(bw + nb) * JJ + j) * 16 + eg * 4;
        atomicAdd(&sp[0], acc4[nb].x);
        atomicAdd(&sp[1], acc4[nb].y);
        atomicAdd(&sp[2], acc4[nb].z);
        atomicAdd(&sp[3], acc4[nb].w);
      } else {
        float* sp = sdst + (size_t)ic * SJE +
                    ((size_t)(bw + nb) * JJ + j) * 16 + eg * 4;
        *reinterpret_cast<float4*>(sp) = acc4[nb];
      }
    }
  }
}

// fused: reduce over 128 i-chunk partials + squash + output/o_eff update
__global__ __launch_bounds__(256)
void finish_pass(const float* __restrict__ part, float* __restrict__ o_eff,
                 float* __restrict__ out, int pass) {
  const int idx = blockIdx.x * 256 + threadIdx.x;   // < 40960; 16 lanes = one (b,j)
  float a = 0.f;
#pragma unroll 8
  for (int k = 0; k < ICHUNKS; ++k) a += part[(size_t)k * SJE + idx];
  if (pass == 0) a *= 0.1f;                         // PASS0 defers c==0.1 scale
  const float s2 = rsum16(a * a);
  const float scale = s2 / ((1.f + s2) * sqrtf(s2 + 1e-7f));
  const float v = scale * a;
  if (pass == 0) o_eff[idx] = v;
  else if (pass == 1) o_eff[idx] += v;
  else out[(size_t)(idx >> 4) * 2064 + (idx & 15)] = v;
}

__global__ __launch_bounds__(256)
void squash_update(const float* __restrict__ s, float* __restrict__ o_eff,
                   float* __restrict__ out, int pass) {
  const int idx = blockIdx.x * blockDim.x + threadIdx.x;
  if (idx >= BB * JJ) return;
  const float* sp = s + (size_t)idx * 16;
  const float pre = (pass == 0) ? 0.1f : 1.f;
  float v[16];
  float s2 = 0.f;
#pragma unroll
  for (int e = 0; e < 16; ++e) { v[e] = pre * sp[e]; s2 = fmaf(v[e], v[e], s2); }
  const float scale = s2 / ((1.f + s2) * sqrtf(s2 + 1e-7f));
  if (pass == 0) {
    float* op = o_eff + (size_t)idx * 16;
#pragma unroll
    for (int e = 0; e < 16; ++e) op[e] = scale * v[e];
  } else if (pass == 1) {
    float* op = o_eff + (size_t)idx * 16;
#pragma unroll
    for (int e = 0; e < 16; ++e) op[e] += scale * v[e];
  } else {
    float* dst = out + (size_t)idx * 2064;
#pragma unroll
    for (int e = 0; e < 16; ++e) dst[e] = scale * v[e];
  }
}

extern "C" void kernel_launch(void* const* d_in, const int* in_sizes, int n_in,
                              void* d_out, int out_size, void* d_ws, size_t ws_size,
                              hipStream_t stream) {
  const float* x = (const float*)d_in[0];   // [256,2048,8]
  const float* W = (const float*)d_in[1];   // [10,2048,16,8]
  float* out = (float*)d_out;               // [256,10,2064]
  float* ws = (float*)d_ws;

  const dim3 grid(ICHUNKS, BB / BBLK);      // (128, 8): XCD = ic % 8
  const size_t need = ((size_t)ICHUNKS * SJE + SJE) * sizeof(float); // ~21.1 MB

  if (ws_size >= need) {
    float* part = ws;
    float* oe   = ws + (size_t)ICHUNKS * SJE;
    pass0_mfma<<<dim3(32, 16), 256, 0, stream>>>(x, W, part);
    finish_pass<<<SJE / 256, 256, 0, stream>>>(part, oe, out, 0);
    routing_pass<1, false><<<grid, 256, 0, stream>>>(x, W, oe, part, nullptr);
    finish_pass<<<SJE / 256, 256, 0, stream>>>(part, oe, out, 1);
    routing_pass<2, false><<<grid, 256, 0, stream>>>(x, W, oe, part, out);
    finish_pass<<<SJE / 256, 256, 0, stream>>>(part, oe, out, 2);
  } else {
    // atomic fallback: PASS0 accumulates raw sums; 0.1 applied in squash_update
    float* s0 = ws;
    float* s1 = ws + SJE;
    float* s2 = ws + 2 * SJE;
    float* oe = ws + 3 * SJE;
    hipMemsetAsync(ws, 0, (size_t)4 * SJE * sizeof(float), stream);
    routing_pass<0, true><<<grid, 256, 0, stream>>>(x, W, nullptr, s0, nullptr);
    squash_update<<<10, 256, 0, stream>>>(s0, oe, out, 0);
    routing_pass<1, true><<<grid, 256, 0, stream>>>(x, W, oe, s1, nullptr);
    squash_update<<<10, 256, 0, stream>>>(s1, oe, out, 1);
    routing_pass<2, true><<<grid, 256, 0, stream>>>(x, W, oe, s2, out);
    squash_update<<<10, 256, 0, stream>>>(s2, oe, out, 2);
  }
}

// Round 16
// 170.381 us; speedup vs baseline: 1.3610x; 1.0572x over previous
//
#include <hip/hip_runtime.h>
#include <math.h>

#define II 2048
#define BB 256
#define JJ 10
#define ICH 16            // i's per block (PASS1/2)
#define ICHUNKS (II/ICH)  // 128
#define BBLK 32           // b's per block (4 waves x 8)
#define NBW 8             // b's per wave
#define SJE (BB*JJ*16)    // 40960

typedef __attribute__((address_space(3))) unsigned lds_u32;
typedef __attribute__((address_space(1))) const unsigned glb_u32;
typedef float v2f __attribute__((ext_vector_type(2)));
typedef _Float16 h2 __attribute__((ext_vector_type(2)));
typedef _Float16 h4 __attribute__((ext_vector_type(4)));
typedef _Float16 h8 __attribute__((ext_vector_type(8)));
typedef __attribute__((ext_vector_type(4))) float f32x4;

__device__ __forceinline__ void gload16(const void* g, void* l) {
  __builtin_amdgcn_global_load_lds((glb_u32*)g, (lds_u32*)l, 16, 0, 0);
}

// DPP row (16-lane) rotate: VALU-pipe cross-lane, no LDS traffic.
template<int N>
__device__ __forceinline__ float rrot16(float v) {
  const int i = __float_as_int(v);
  return __int_as_float(__builtin_amdgcn_update_dpp(i, i, 0x120 + N, 0xF, 0xF, false));
}
__device__ __forceinline__ float rsum16(float v) {
  v += rrot16<8>(v); v += rrot16<4>(v); v += rrot16<2>(v); v += rrot16<1>(v);
  return v;
}
__device__ __forceinline__ float xor16swz(float v) {  // lane ^ 16 (within 32-halves)
  return __int_as_float(__builtin_amdgcn_ds_swizzle(__float_as_int(v), 0x401F));
}

__device__ __forceinline__ float dot8(const h2* w, h2 x0, h2 x1, h2 x2, h2 x3) {
#if __has_builtin(__builtin_amdgcn_fdot2)
  float a = __builtin_amdgcn_fdot2(w[0], x0, 0.f, false);
  a = __builtin_amdgcn_fdot2(w[1], x1, a, false);
  a = __builtin_amdgcn_fdot2(w[2], x2, a, false);
  a = __builtin_amdgcn_fdot2(w[3], x3, a, false);
  return a;
#else
  float a = (float)w[0].x * (float)x0.x + (float)w[0].y * (float)x0.y;
  a = fmaf((float)w[1].x, (float)x1.x, a); a = fmaf((float)w[1].y, (float)x1.y, a);
  a = fmaf((float)w[2].x, (float)x2.x, a); a = fmaf((float)w[2].y, (float)x2.y, a);
  a = fmaf((float)w[3].x, (float)x3.x, a); a = fmaf((float)w[3].y, (float)x3.y, a);
  return a;
#endif
}

// -------- prep: fp32 -> f16 copies of x and W in ws --------
#define XF4 (BB * II * 8 / 4)        // 1048576 float4 slots
#define WF4 (JJ * II * 128 / 4)      // 655360
__global__ __launch_bounds__(256)
void prep_half(const float* __restrict__ x, const float* __restrict__ W,
               _Float16* __restrict__ xh, _Float16* __restrict__ wh) {
  for (int s = blockIdx.x * 256 + threadIdx.x; s < XF4 + WF4; s += gridDim.x * 256) {
    const float4 v = (s < XF4) ? *reinterpret_cast<const float4*>(x + (size_t)s * 4)
                               : *reinterpret_cast<const float4*>(W + (size_t)(s - XF4) * 4);
    h4 o; o.x = (_Float16)v.x; o.y = (_Float16)v.y; o.z = (_Float16)v.z; o.w = (_Float16)v.w;
    _Float16* dst = (s < XF4) ? (xh + (size_t)s * 4) : (wh + (size_t)(s - XF4) * 4);
    *reinterpret_cast<h4*>(dst) = o;
  }
}

// -------- PASS0 as f16 MFMA GEMM (s0 = x.W^T over (i,d); c==0.1 deferred) --------
__global__ __launch_bounds__(256)
void pass0_mfma(const _Float16* __restrict__ xh, const _Float16* __restrict__ wh,
                float* __restrict__ part) {
  const int t = threadIdx.x, wid = t >> 6, lane = t & 63;
  const int lg = lane >> 4, lm = lane & 15;
  const int chunk = blockIdx.x * 4 + wid;      // 0..127
  const int mb = blockIdx.y * 16;
  f32x4 acc0 = {0,0,0,0}, acc1 = {0,0,0,0}, acc2 = {0,0,0,0}, acc3 = {0,0,0,0};
  f32x4 acc4_ = {0,0,0,0}, acc5 = {0,0,0,0}, acc6 = {0,0,0,0}, acc7 = {0,0,0,0};
  f32x4 acc8 = {0,0,0,0}, acc9 = {0,0,0,0};
  const int ibase = chunk * 16;
#pragma unroll
  for (int ks = 0; ks < 4; ++ks) {
    const int i = ibase + ks * 4 + lg;
    const h8 a = *reinterpret_cast<const h8*>(xh + ((size_t)(mb + lm) * II + i) * 8);
#define MM(J, ACC)                                                              \
    {                                                                           \
      const h8 bv = *reinterpret_cast<const h8*>(                               \
          wh + (((size_t)(J) * II + i) * 16 + lm) * 8);                         \
      ACC = __builtin_amdgcn_mfma_f32_16x16x32_f16(a, bv, ACC, 0, 0, 0);        \
    }
    MM(0, acc0) MM(1, acc1) MM(2, acc2) MM(3, acc3) MM(4, acc4_)
    MM(5, acc5) MM(6, acc6) MM(7, acc7) MM(8, acc8) MM(9, acc9)
#undef MM
  }
  float* base = part + (size_t)chunk * SJE;
#define ST(J, ACC)                                                        \
  {                                                                       \
    _Pragma("unroll")                                                     \
    for (int r = 0; r < 4; ++r)                                           \
      base[((size_t)(mb + lg * 4 + r) * JJ + (J)) * 16 + lm] = ACC[r];    \
  }
  ST(0, acc0) ST(1, acc1) ST(2, acc2) ST(3, acc3) ST(4, acc4_)
  ST(5, acc5) ST(6, acc6) ST(7, acc7) ST(8, acc8) ST(9, acc9)
#undef ST
}

// -------- PASS1/2: barrier-free, f16 data, W register-prefetch pipeline --------
union H64 { uint4 q4[4]; h2 p[16]; };   // one lane's W slice for one i (64 B)

template<int PASS>
__global__ __launch_bounds__(256, 1)
void routing_h(const _Float16* __restrict__ xh, const _Float16* __restrict__ wh,
               const float* __restrict__ o_eff, float* __restrict__ sdst,
               float* __restrict__ out) {
  __shared__ __align__(16) _Float16 x_lds[BBLK * ICH * 8];        // 8 KB
  __shared__ _Float16 c_tile[(PASS == 2) ? (BBLK * JJ * 18) : 4]; // 11.25 KB

  const int t = threadIdx.x;
  const int wid = t >> 6;
  const int lane = t & 63;
  const int eg = lane >> 4;
  const int j = lane & 15;
  const int jv = (j < JJ);
  const int jr = jv ? j : 0;
  const int ic = blockIdx.x;           // XCD = ic % 8
  const int b0 = blockIdx.y * BBLK;
  const int bw = __builtin_amdgcn_readfirstlane(b0 + wid * NBW);
  const int i0 = ic * ICH;

  const _Float16* whbase = wh + ((size_t)jr * II + i0) * 128 + eg * 32;

  float4 o4[NBW];
#pragma unroll
  for (int nb = 0; nb < NBW; ++nb)
    o4[nb] = *reinterpret_cast<const float4*>(
        o_eff + ((size_t)(bw + nb) * JJ + jr) * 16 + eg * 4);

  float4 acc4[NBW];
#pragma unroll
  for (int nb = 0; nb < NBW; ++nb) acc4[nb] = make_float4(0.f, 0.f, 0.f, 0.f);

  // x stage: 512 slots of 16 B (one (b,i) row of 8 halves each), lane-linear
#pragma unroll
  for (int k = 0; k < 2; ++k) {
    const int s = k * 256 + t;
    const int bl = s >> 4, il = s & 15;
    gload16(xh + ((size_t)(b0 + bl) * II + i0 + il) * 8,
            &x_lds[(size_t)(k * 256 + wid * 64) * 8]);
  }
  __syncthreads();   // the ONLY main-path barrier

  H64 wvA, wvB;
  auto loadw = [&](H64& wv, int il) {
    const _Float16* wp = whbase + il * 128;
#pragma unroll
    for (int r = 0; r < 4; ++r)
      wv.q4[r] = *reinterpret_cast<const uint4*>(wp + r * 8);
  };

  auto compute_i = [&](const H64& wv, int il) {
#pragma unroll
    for (int nb = 0; nb < NBW; ++nb) {
      const h2* xp = reinterpret_cast<const h2*>(
          &x_lds[((wid * NBW + nb) * ICH + il) * 8]);       // wave-uniform -> broadcast
      const h2 x0 = xp[0], x1 = xp[1], x2 = xp[2], x3 = xp[3];
      const float u0 = dot8(wv.p + 0,  x0, x1, x2, x3);
      const float u1 = dot8(wv.p + 4,  x0, x1, x2, x3);
      const float u2 = dot8(wv.p + 8,  x0, x1, x2, x3);
      const float u3 = dot8(wv.p + 12, x0, x1, x2, x3);
      float lp = o4[nb].x * u0;
      lp = fmaf(o4[nb].y, u1, lp);
      lp = fmaf(o4[nb].z, u2, lp);
      lp = fmaf(o4[nb].w, u3, lp);
      lp += xor16swz(lp);                       // reduce over 4 e-groups
      lp += __shfl_xor(lp, 32);
      const float pp = jv ? __expf(lp) : 0.f;   // no max-sub (logits bounded)
      const float su = rsum16(pp);
      const float c = pp * __builtin_amdgcn_rcpf(su);
      acc4[nb].x = fmaf(c, u0, acc4[nb].x);
      acc4[nb].y = fmaf(c, u1, acc4[nb].y);
      acc4[nb].z = fmaf(c, u2, acc4[nb].z);
      acc4[nb].w = fmaf(c, u3, acc4[nb].w);
      if (PASS == 2) {
        if (eg == 0 && jv)
          c_tile[((wid * NBW + nb) * JJ + j) * 18 + il] = (_Float16)c;
      }
    }
  };

  loadw(wvA, 0);
#pragma unroll 1
  for (int il2 = 0; il2 < ICH; il2 += 2) {
    loadw(wvB, il2 + 1);          // issue i+1 loads before computing i
    compute_i(wvA, il2);
    if (il2 + 2 < ICH) loadw(wvA, il2 + 2);
    compute_i(wvB, il2 + 1);
  }

  if (PASS == 2) {
    __syncthreads();
    for (int s = t; s < BBLK * JJ * ICH; s += 256) {
      const int row = s >> 4, col = s & 15;
      const int bb = row / 10, jj = row - bb * 10;
      out[((size_t)(b0 + bb) * JJ + jj) * 2064 + 16 + i0 + col] =
          (float)c_tile[row * 18 + col];
    }
  }

  if (jv) {
#pragma unroll
    for (int nb = 0; nb < NBW; ++nb) {
      float* sp = sdst + (size_t)ic * SJE +
                  ((size_t)(bw + nb) * JJ + j) * 16 + eg * 4;
      *reinterpret_cast<float4*>(sp) = acc4[nb];
    }
  }
}

// -------- fp32 atomic fallback (round-13-proven), used only if ws too small --------
template<int PASS>
__global__ __launch_bounds__(256, 1)
void routing_pass_atomic(const float* __restrict__ x, const float* __restrict__ W,
                         const float* __restrict__ o_eff, float* __restrict__ sdst,
                         float* __restrict__ out) {
  __shared__ __align__(16) float x_lds[BBLK * ICH * 8];
  __shared__ _Float16 c_tile[(PASS == 2) ? (BBLK * JJ * 18) : 4];

  const int t = threadIdx.x;
  const int wid = t >> 6;
  const int lane = t & 63;
  const int eg = lane >> 4;
  const int j = lane & 15;
  const int jv = (j < JJ);
  const int jr = jv ? j : 0;
  const int ic = blockIdx.x;
  const int b0 = blockIdx.y * BBLK;
  const int bw = __builtin_amdgcn_readfirstlane(b0 + wid * NBW);
  const int i0 = ic * ICH;
  const float* wbase = W + ((size_t)jr * II + i0) * 128 + eg * 32;

  float4 o4[NBW];
  if (PASS > 0) {
#pragma unroll
    for (int nb = 0; nb < NBW; ++nb)
      o4[nb] = *reinterpret_cast<const float4*>(
          o_eff + ((size_t)(bw + nb) * JJ + jr) * 16 + eg * 4);
  }
  float4 acc4[NBW];
#pragma unroll
  for (int nb = 0; nb < NBW; ++nb) acc4[nb] = make_float4(0.f, 0.f, 0.f, 0.f);

#pragma unroll
  for (int k = 0; k < 4; ++k) {
    const int s = k * 256 + t;
    const int bl = s >> 5, rem = s & 31, il = rem >> 1, h = rem & 1;
    gload16(x + ((size_t)(b0 + bl) * II + i0 + il) * 8 + h * 4,
            &x_lds[(k * 256 + wid * 64) * 4]);
  }
  __syncthreads();

#pragma unroll 1
  for (int il = 0; il < ICH; ++il) {
    const float* wp = wbase + il * 128;
    float4 wv[8];
#pragma unroll
    for (int r = 0; r < 8; ++r)
      wv[r] = *reinterpret_cast<const float4*>(wp + r * 4);
#pragma unroll
    for (int nb = 0; nb < NBW; ++nb) {
      const float* xp = &x_lds[((wid * NBW + nb) * ICH + il) * 8];
      const float4 xa = *reinterpret_cast<const float4*>(xp);
      const float4 xb = *reinterpret_cast<const float4*>(xp + 4);
#define DOT8F(q, dst)                                  \
      float dst = wv[2*(q)].x * xa.x;                  \
      dst = fmaf(wv[2*(q)].y, xa.y, dst);              \
      dst = fmaf(wv[2*(q)].z, xa.z, dst);              \
      dst = fmaf(wv[2*(q)].w, xa.w, dst);              \
      dst = fmaf(wv[2*(q)+1].x, xb.x, dst);            \
      dst = fmaf(wv[2*(q)+1].y, xb.y, dst);            \
      dst = fmaf(wv[2*(q)+1].z, xb.z, dst);            \
      dst = fmaf(wv[2*(q)+1].w, xb.w, dst);
      DOT8F(0, u0) DOT8F(1, u1) DOT8F(2, u2) DOT8F(3, u3)
#undef DOT8F
      float c;
      if (PASS == 0) {
        c = 0.1f;
      } else {
        float lp = o4[nb].x * u0;
        lp = fmaf(o4[nb].y, u1, lp);
        lp = fmaf(o4[nb].z, u2, lp);
        lp = fmaf(o4[nb].w, u3, lp);
        lp += xor16swz(lp);
        lp += __shfl_xor(lp, 32);
        const float pp = jv ? __expf(lp) : 0.f;
        const float su = rsum16(pp);
        c = pp * __builtin_amdgcn_rcpf(su);
      }
      acc4[nb].x = fmaf(c, u0, acc4[nb].x);
      acc4[nb].y = fmaf(c, u1, acc4[nb].y);
      acc4[nb].z = fmaf(c, u2, acc4[nb].z);
      acc4[nb].w = fmaf(c, u3, acc4[nb].w);
      if (PASS == 2) {
        if (eg == 0 && jv)
          c_tile[((wid * NBW + nb) * JJ + j) * 18 + il] = (_Float16)c;
      }
    }
  }

  if (PASS == 2) {
    __syncthreads();
    for (int s = t; s < BBLK * JJ * ICH; s += 256) {
      const int row = s >> 4, col = s & 15;
      const int bb = row / 10, jj = row - bb * 10;
      out[((size_t)(b0 + bb) * JJ + jj) * 2064 + 16 + i0 + col] =
          (float)c_tile[row * 18 + col];
    }
  }

  if (jv) {
#pragma unroll
    for (int nb = 0; nb < NBW; ++nb) {
      float* sp = sdst + ((size_t)(bw + nb) * JJ + j) * 16 + eg * 4;
      atomicAdd(&sp[0], acc4[nb].x);
      atomicAdd(&sp[1], acc4[nb].y);
      atomicAdd(&sp[2], acc4[nb].z);
      atomicAdd(&sp[3], acc4[nb].w);
    }
  }
}

// fused: reduce over 128 i-chunk partials + squash + output/o_eff update
__global__ __launch_bounds__(256)
void finish_pass(const float* __restrict__ part, float* __restrict__ o_eff,
                 float* __restrict__ out, int pass) {
  const int idx = blockIdx.x * 256 + threadIdx.x;
  float a = 0.f;
#pragma unroll 8
  for (int k = 0; k < ICHUNKS; ++k) a += part[(size_t)k * SJE + idx];
  if (pass == 0) a *= 0.1f;
  const float s2 = rsum16(a * a);
  const float scale = s2 / ((1.f + s2) * sqrtf(s2 + 1e-7f));
  const float v = scale * a;
  if (pass == 0) o_eff[idx] = v;
  else if (pass == 1) o_eff[idx] += v;
  else out[(size_t)(idx >> 4) * 2064 + (idx & 15)] = v;
}

__global__ __launch_bounds__(256)
void squash_update(const float* __restrict__ s, float* __restrict__ o_eff,
                   float* __restrict__ out, int pass) {
  const int idx = blockIdx.x * blockDim.x + threadIdx.x;
  if (idx >= BB * JJ) return;
  const float* sp = s + (size_t)idx * 16;
  const float pre = (pass == 0) ? 0.1f : 1.f;
  float v[16];
  float s2 = 0.f;
#pragma unroll
  for (int e = 0; e < 16; ++e) { v[e] = pre * sp[e]; s2 = fmaf(v[e], v[e], s2); }
  const float scale = s2 / ((1.f + s2) * sqrtf(s2 + 1e-7f));
  if (pass == 0) {
    float* op = o_eff + (size_t)idx * 16;
#pragma unroll
    for (int e = 0; e < 16; ++e) op[e] = scale * v[e];
  } else if (pass == 1) {
    float* op = o_eff + (size_t)idx * 16;
#pragma unroll
    for (int e = 0; e < 16; ++e) op[e] += scale * v[e];
  } else {
    float* dst = out + (size_t)idx * 2064;
#pragma unroll
    for (int e = 0; e < 16; ++e) dst[e] = scale * v[e];
  }
}

extern "C" void kernel_launch(void* const* d_in, const int* in_sizes, int n_in,
                              void* d_out, int out_size, void* d_ws, size_t ws_size,
                              hipStream_t stream) {
  const float* x = (const float*)d_in[0];   // [256,2048,8]
  const float* W = (const float*)d_in[1];   // [10,2048,16,8]
  float* out = (float*)d_out;               // [256,10,2064]
  float* ws = (float*)d_ws;

  const dim3 grid(ICHUNKS, BB / BBLK);      // (128, 8): XCD = ic % 8
  // ws: part | oe | xh | wh
  const size_t part_f = (size_t)ICHUNKS * SJE;              // 5242880 floats
  const size_t xh_f   = (size_t)BB * II * 8 / 2;            // 2097152 floats (as halves)
  const size_t wh_f   = (size_t)JJ * II * 128 / 2;          // 1310720
  const size_t need = (part_f + SJE + xh_f + wh_f) * sizeof(float); // ~34.8 MB

  if (ws_size >= need) {
    float* part = ws;
    float* oe   = ws + part_f;
    _Float16* xh = (_Float16*)(ws + part_f + SJE);
    _Float16* wh = (_Float16*)(ws + part_f + SJE + xh_f);
    prep_half<<<2048, 256, 0, stream>>>(x, W, xh, wh);
    pass0_mfma<<<dim3(32, 16), 256, 0, stream>>>(xh, wh, part);
    finish_pass<<<SJE / 256, 256, 0, stream>>>(part, oe, out, 0);
    routing_h<1><<<grid, 256, 0, stream>>>(xh, wh, oe, part, nullptr);
    finish_pass<<<SJE / 256, 256, 0, stream>>>(part, oe, out, 1);
    routing_h<2><<<grid, 256, 0, stream>>>(xh, wh, oe, part, out);
    finish_pass<<<SJE / 256, 256, 0, stream>>>(part, oe, out, 2);
  } else {
    // atomic fallback (fp32, round-13-proven); PASS0 applies c=0.1 via squash pre
    float* s0 = ws;
    float* s1 = ws + SJE;
    float* s2 = ws + 2 * SJE;
    float* oe = ws + 3 * SJE;
    hipMemsetAsync(ws, 0, (size_t)4 * SJE * sizeof(float), stream);
    routing_pass_atomic<0><<<grid, 256, 0, stream>>>(x, W, nullptr, s0, nullptr);
    squash_update<<<10, 256, 0, stream>>>(s0, oe, out, 0);
    routing_pass_atomic<1><<<grid, 256, 0, stream>>>(x, W, oe, s1, nullptr);
    squash_update<<<10, 256, 0, stream>>>(s1, oe, out, 1);
    routing_pass_atomic<2><<<grid, 256, 0, stream>>>(x, W, oe, s2, out);
    squash_update<<<10, 256, 0, stream>>>(s2, oe, out, 2);
  }
}

// Round 17
// 138.785 us; speedup vs baseline: 1.6709x; 1.2277x over previous
//
#include <hip/hip_runtime.h>
#include <math.h>

#define II 2048
#define BB 256
#define JJ 10
#define ICH 16            // i's per block
#define ICHUNKS (II/ICH)  // 128
#define SJE (BB*JJ*16)    // 40960

typedef __attribute__((address_space(3))) unsigned lds_u32;
typedef __attribute__((address_space(1))) const unsigned glb_u32;
typedef _Float16 h4 __attribute__((ext_vector_type(4)));
typedef _Float16 h8 __attribute__((ext_vector_type(8)));
typedef __attribute__((ext_vector_type(4))) float f32x4;

__device__ __forceinline__ void gload16(const void* g, void* l) {
  __builtin_amdgcn_global_load_lds((glb_u32*)g, (lds_u32*)l, 16, 0, 0);
}

// DPP row (16-lane) rotate: VALU-pipe cross-lane, no LDS traffic.
template<int N>
__device__ __forceinline__ float rrot16(float v) {
  const int i = __float_as_int(v);
  return __int_as_float(__builtin_amdgcn_update_dpp(i, i, 0x120 + N, 0xF, 0xF, false));
}
__device__ __forceinline__ float rsum16(float v) {
  v += rrot16<8>(v); v += rrot16<4>(v); v += rrot16<2>(v); v += rrot16<1>(v);
  return v;
}
__device__ __forceinline__ float xor16swz(float v) {  // lane ^ 16 (within 32-halves)
  return __int_as_float(__builtin_amdgcn_ds_swizzle(__float_as_int(v), 0x401F));
}

// -------- prep: fp32 -> f16 copies of x and W in ws --------
#define XF4 (BB * II * 8 / 4)        // 1048576 float4 slots
#define WF4 (JJ * II * 128 / 4)      // 655360
__global__ __launch_bounds__(256)
void prep_half(const float* __restrict__ x, const float* __restrict__ W,
               _Float16* __restrict__ xh, _Float16* __restrict__ wh) {
  for (int s = blockIdx.x * 256 + threadIdx.x; s < XF4 + WF4; s += gridDim.x * 256) {
    const float4 v = (s < XF4) ? *reinterpret_cast<const float4*>(x + (size_t)s * 4)
                               : *reinterpret_cast<const float4*>(W + (size_t)(s - XF4) * 4);
    h4 o; o.x = (_Float16)v.x; o.y = (_Float16)v.y; o.z = (_Float16)v.z; o.w = (_Float16)v.w;
    _Float16* dst = (s < XF4) ? (xh + (size_t)s * 4) : (wh + (size_t)(s - XF4) * 4);
    *reinterpret_cast<h4*>(dst) = o;
  }
}

// -------- PASS0 as f16 MFMA GEMM (s0 = x.W^T over (i,d); c==0.1 deferred) --------
__global__ __launch_bounds__(256)
void pass0_mfma(const _Float16* __restrict__ xh, const _Float16* __restrict__ wh,
                float* __restrict__ part) {
  const int t = threadIdx.x, wid = t >> 6, lane = t & 63;
  const int lg = lane >> 4, lm = lane & 15;
  const int chunk = blockIdx.x * 4 + wid;      // 0..127
  const int mb = blockIdx.y * 16;
  f32x4 acc0 = {0,0,0,0}, acc1 = {0,0,0,0}, acc2 = {0,0,0,0}, acc3 = {0,0,0,0};
  f32x4 acc4_ = {0,0,0,0}, acc5 = {0,0,0,0}, acc6 = {0,0,0,0}, acc7 = {0,0,0,0};
  f32x4 acc8 = {0,0,0,0}, acc9 = {0,0,0,0};
  const int ibase = chunk * 16;
#pragma unroll
  for (int ks = 0; ks < 4; ++ks) {
    const int i = ibase + ks * 4 + lg;
    const h8 a = *reinterpret_cast<const h8*>(xh + ((size_t)(mb + lm) * II + i) * 8);
#define MM(J, ACC)                                                              \
    {                                                                           \
      const h8 bv = *reinterpret_cast<const h8*>(                               \
          wh + (((size_t)(J) * II + i) * 16 + lm) * 8);                         \
      ACC = __builtin_amdgcn_mfma_f32_16x16x32_f16(a, bv, ACC, 0, 0, 0);        \
    }
    MM(0, acc0) MM(1, acc1) MM(2, acc2) MM(3, acc3) MM(4, acc4_)
    MM(5, acc5) MM(6, acc6) MM(7, acc7) MM(8, acc8) MM(9, acc9)
#undef MM
  }
  float* base = part + (size_t)chunk * SJE;
#define ST(J, ACC)                                                        \
  {                                                                       \
    _Pragma("unroll")                                                     \
    for (int r = 0; r < 4; ++r)                                           \
      base[((size_t)(mb + lg * 4 + r) * JJ + (J)) * 16 + lm] = ACC[r];    \
  }
  ST(0, acc0) ST(1, acc1) ST(2, acc2) ST(3, acc3) ST(4, acc4_)
  ST(5, acc5) ST(6, acc6) ST(7, acc7) ST(8, acc8) ST(9, acc9)
#undef ST
}

// -------- PASS1/2: swapped-operand MFMA routing --------
// Per i, wave computes uh[e, b] for 16 b's via 10 MFMA:
//   A = W_j (rows m=e: lanes<16 hold W[j,i,e=lm,0..7], lanes>=16 ZERO)
//   B = x   (cols n=b: lanes<16 hold x[b=lm,i,0..7],   lanes>=16 ZERO)
//   C_j: lane holds col b=lm, rows e=eg*4+r  -> lane = (b, eg), j in regs.
// Softmax over j is register-local; e-reduce = xor16 + xor32 per j.
// Block = 2 waves (i-split 8+8, same 16 b's); acc combined via LDS.
template<int PASS>
__global__ __launch_bounds__(128, 1)
void routing_mfma(const _Float16* __restrict__ xh, const _Float16* __restrict__ wh,
                  const float* __restrict__ o_eff, float* __restrict__ part,
                  float* __restrict__ out) {
  __shared__ __align__(16) float s_acc[16 * 164];                  // 10.25 KB (pad 164)
  __shared__ _Float16 c_tile[(PASS == 2) ? (16 * JJ * ICH) : 4];   // 5 KB (PASS2)

  const int t = threadIdx.x;
  const int w = t >> 6;                // wave 0/1
  const int lane = t & 63;
  const int lm = lane & 15;            // b-sub (MFMA col)
  const int eg = lane >> 4;            // e-group (MFMA row quad)
  const int ic = blockIdx.x;           // i-chunk (XCD = ic % 8)
  const int b0 = blockIdx.y * 16;
  const int b = b0 + lm;
  const int i0 = ic * ICH;

  // o[b, j, eg-slice], i-invariant
  float4 o[JJ];
#pragma unroll
  for (int j = 0; j < JJ; ++j)
    o[j] = *reinterpret_cast<const float4*>(
        o_eff + ((size_t)b * JJ + j) * 16 + eg * 4);

  f32x4 acc[JJ];
#pragma unroll
  for (int j = 0; j < JJ; ++j) acc[j] = f32x4{0.f, 0.f, 0.f, 0.f};

  const f32x4 z4 = {0.f, 0.f, 0.f, 0.f};
  h8 xfrag = {0, 0, 0, 0, 0, 0, 0, 0};   // lanes>=16 stay zero forever
  h8 wf0   = {0, 0, 0, 0, 0, 0, 0, 0};
  h8 wf1   = {0, 0, 0, 0, 0, 0, 0, 0};

  const _Float16* xrow = xh + (size_t)b * II * 8;

#pragma unroll 1
  for (int ii = 0; ii < ICH / 2; ++ii) {
    const int i = i0 + w * (ICH / 2) + ii;
    const int il = w * (ICH / 2) + ii;
    if (lane < 16) {
      xfrag = *reinterpret_cast<const h8*>(xrow + (size_t)i * 8);
      wf0   = *reinterpret_cast<const h8*>(wh + (((size_t)0 * II + i) * 16 + lm) * 8);
    }
    f32x4 uh[JJ];
#pragma unroll
    for (int j = 0; j < JJ; ++j) {
      if (j + 1 < JJ) {
        h8& dst = ((j & 1) == 0) ? wf1 : wf0;
        if (lane < 16)
          dst = *reinterpret_cast<const h8*>(
              wh + (((size_t)(j + 1) * II + i) * 16 + lm) * 8);
      }
      const h8& src = ((j & 1) == 0) ? wf0 : wf1;
      uh[j] = __builtin_amdgcn_mfma_f32_16x16x32_f16(src, xfrag, z4, 0, 0, 0);
    }
    // logits: partial over this lane's 4 e's, then e-reduce across 4 groups
    float cj[JJ];
    float D = 0.f;
#pragma unroll
    for (int j = 0; j < JJ; ++j) {
      float v = o[j].x * uh[j][0];
      v = fmaf(o[j].y, uh[j][1], v);
      v = fmaf(o[j].z, uh[j][2], v);
      v = fmaf(o[j].w, uh[j][3], v);
      v += xor16swz(v);
      v += __shfl_xor(v, 32);
      const float pp = __expf(v);      // no max-sub: logits bounded, fp32 safe
      cj[j] = pp;
      D += pp;
    }
    const float rD = __builtin_amdgcn_rcpf(D);
#pragma unroll
    for (int j = 0; j < JJ; ++j) {
      const float c = cj[j] * rD;
      cj[j] = c;
      acc[j][0] = fmaf(c, uh[j][0], acc[j][0]);
      acc[j][1] = fmaf(c, uh[j][1], acc[j][1]);
      acc[j][2] = fmaf(c, uh[j][2], acc[j][2]);
      acc[j][3] = fmaf(c, uh[j][3], acc[j][3]);
    }
    if (PASS == 2) {
      // distribute c writes over eg groups: eg0->j0-2, eg1->j3-5, eg2->j6-8, eg3->j9
#pragma unroll
      for (int j = 0; j < JJ; ++j) {
        const int owner = (j >= 9) ? 3 : (j / 3);
        if (eg == owner)
          c_tile[(lm * JJ + j) * ICH + il] = (_Float16)cj[j];
      }
    }
  }

  // combine the two waves' acc and store part
  if (w == 0) {
#pragma unroll
    for (int j = 0; j < JJ; ++j)
      *reinterpret_cast<f32x4*>(&s_acc[lm * 164 + j * 16 + eg * 4]) = acc[j];
  }
  __syncthreads();
  if (w == 1) {
#pragma unroll
    for (int j = 0; j < JJ; ++j) {
      f32x4 v = *reinterpret_cast<const f32x4*>(&s_acc[lm * 164 + j * 16 + eg * 4]);
      v += acc[j];
      *reinterpret_cast<f32x4*>(
          part + (size_t)ic * SJE + ((size_t)b * JJ + j) * 16 + eg * 4) = v;
    }
  }

  if (PASS == 2) {
    // coalesced c out: 160 rows x 16 i-floats
    for (int s = t; s < 16 * JJ * (ICH / 4); s += 128) {
      const int row = s >> 2, q = s & 3;
      const int bb = row / JJ, jj = row - bb * JJ;
      const h4 cv = *reinterpret_cast<const h4*>(&c_tile[row * ICH + q * 4]);
      float4 ov;
      ov.x = (float)cv.x; ov.y = (float)cv.y; ov.z = (float)cv.z; ov.w = (float)cv.w;
      *reinterpret_cast<float4*>(
          out + ((size_t)(b0 + bb) * JJ + jj) * 2064 + 16 + i0 + q * 4) = ov;
    }
  }
}

// fused: reduce over 128 i-chunk partials + squash + output/o_eff update
__global__ __launch_bounds__(256)
void finish_pass(const float* __restrict__ part, float* __restrict__ o_eff,
                 float* __restrict__ out, int pass) {
  const int idx = blockIdx.x * 256 + threadIdx.x;
  float a = 0.f;
#pragma unroll 8
  for (int k = 0; k < ICHUNKS; ++k) a += part[(size_t)k * SJE + idx];
  if (pass == 0) a *= 0.1f;
  const float s2 = rsum16(a * a);
  const float scale = s2 / ((1.f + s2) * sqrtf(s2 + 1e-7f));
  const float v = scale * a;
  if (pass == 0) o_eff[idx] = v;
  else if (pass == 1) o_eff[idx] += v;
  else out[(size_t)(idx >> 4) * 2064 + (idx & 15)] = v;
}

// -------- fp32 atomic fallback (round-13-proven), used only if ws too small --------
#define BBLK 32
#define NBW 8
template<int PASS>
__global__ __launch_bounds__(256, 1)
void routing_pass_atomic(const float* __restrict__ x, const float* __restrict__ W,
                         const float* __restrict__ o_eff, float* __restrict__ sdst,
                         float* __restrict__ out) {
  __shared__ __align__(16) float x_lds[BBLK * ICH * 8];
  __shared__ _Float16 c_tile[(PASS == 2) ? (BBLK * JJ * 18) : 4];

  const int t = threadIdx.x;
  const int wid = t >> 6;
  const int lane = t & 63;
  const int eg = lane >> 4;
  const int j = lane & 15;
  const int jv = (j < JJ);
  const int jr = jv ? j : 0;
  const int ic = blockIdx.x;
  const int b0 = blockIdx.y * BBLK;
  const int bw = __builtin_amdgcn_readfirstlane(b0 + wid * NBW);
  const int i0 = ic * ICH;
  const float* wbase = W + ((size_t)jr * II + i0) * 128 + eg * 32;

  float4 o4[NBW];
  if (PASS > 0) {
#pragma unroll
    for (int nb = 0; nb < NBW; ++nb)
      o4[nb] = *reinterpret_cast<const float4*>(
          o_eff + ((size_t)(bw + nb) * JJ + jr) * 16 + eg * 4);
  }
  float4 acc4[NBW];
#pragma unroll
  for (int nb = 0; nb < NBW; ++nb) acc4[nb] = make_float4(0.f, 0.f, 0.f, 0.f);

#pragma unroll
  for (int k = 0; k < 4; ++k) {
    const int s = k * 256 + t;
    const int bl = s >> 5, rem = s & 31, il = rem >> 1, h = rem & 1;
    gload16(x + ((size_t)(b0 + bl) * II + i0 + il) * 8 + h * 4,
            &x_lds[(k * 256 + wid * 64) * 4]);
  }
  __syncthreads();

#pragma unroll 1
  for (int il = 0; il < ICH; ++il) {
    const float* wp = wbase + il * 128;
    float4 wv[8];
#pragma unroll
    for (int r = 0; r < 8; ++r)
      wv[r] = *reinterpret_cast<const float4*>(wp + r * 4);
#pragma unroll
    for (int nb = 0; nb < NBW; ++nb) {
      const float* xp = &x_lds[((wid * NBW + nb) * ICH + il) * 8];
      const float4 xa = *reinterpret_cast<const float4*>(xp);
      const float4 xb = *reinterpret_cast<const float4*>(xp + 4);
#define DOT8F(q, dst)                                  \
      float dst = wv[2*(q)].x * xa.x;                  \
      dst = fmaf(wv[2*(q)].y, xa.y, dst);              \
      dst = fmaf(wv[2*(q)].z, xa.z, dst);              \
      dst = fmaf(wv[2*(q)].w, xa.w, dst);              \
      dst = fmaf(wv[2*(q)+1].x, xb.x, dst);            \
      dst = fmaf(wv[2*(q)+1].y, xb.y, dst);            \
      dst = fmaf(wv[2*(q)+1].z, xb.z, dst);            \
      dst = fmaf(wv[2*(q)+1].w, xb.w, dst);
      DOT8F(0, u0) DOT8F(1, u1) DOT8F(2, u2) DOT8F(3, u3)
#undef DOT8F
      float c;
      if (PASS == 0) {
        c = 0.1f;
      } else {
        float lp = o4[nb].x * u0;
        lp = fmaf(o4[nb].y, u1, lp);
        lp = fmaf(o4[nb].z, u2, lp);
        lp = fmaf(o4[nb].w, u3, lp);
        lp += xor16swz(lp);
        lp += __shfl_xor(lp, 32);
        const float pp = jv ? __expf(lp) : 0.f;
        const float su = rsum16(pp);
        c = pp * __builtin_amdgcn_rcpf(su);
      }
      acc4[nb].x = fmaf(c, u0, acc4[nb].x);
      acc4[nb].y = fmaf(c, u1, acc4[nb].y);
      acc4[nb].z = fmaf(c, u2, acc4[nb].z);
      acc4[nb].w = fmaf(c, u3, acc4[nb].w);
      if (PASS == 2) {
        if (eg == 0 && jv)
          c_tile[((wid * NBW + nb) * JJ + j) * 18 + il] = (_Float16)c;
      }
    }
  }

  if (PASS == 2) {
    __syncthreads();
    for (int s = t; s < BBLK * JJ * ICH; s += 256) {
      const int row = s >> 4, col = s & 15;
      const int bb = row / 10, jj = row - bb * 10;
      out[((size_t)(b0 + bb) * JJ + jj) * 2064 + 16 + i0 + col] =
          (float)c_tile[row * 18 + col];
    }
  }

  if (jv) {
#pragma unroll
    for (int nb = 0; nb < NBW; ++nb) {
      float* sp = sdst + ((size_t)(bw + nb) * JJ + j) * 16 + eg * 4;
      atomicAdd(&sp[0], acc4[nb].x);
      atomicAdd(&sp[1], acc4[nb].y);
      atomicAdd(&sp[2], acc4[nb].z);
      atomicAdd(&sp[3], acc4[nb].w);
    }
  }
}

__global__ __launch_bounds__(256)
void squash_update(const float* __restrict__ s, float* __restrict__ o_eff,
                   float* __restrict__ out, int pass) {
  const int idx = blockIdx.x * blockDim.x + threadIdx.x;
  if (idx >= BB * JJ) return;
  const float* sp = s + (size_t)idx * 16;
  const float pre = (pass == 0) ? 0.1f : 1.f;
  float v[16];
  float s2 = 0.f;
#pragma unroll
  for (int e = 0; e < 16; ++e) { v[e] = pre * sp[e]; s2 = fmaf(v[e], v[e], s2); }
  const float scale = s2 / ((1.f + s2) * sqrtf(s2 + 1e-7f));
  if (pass == 0) {
    float* op = o_eff + (size_t)idx * 16;
#pragma unroll
    for (int e = 0; e < 16; ++e) op[e] = scale * v[e];
  } else if (pass == 1) {
    float* op = o_eff + (size_t)idx * 16;
#pragma unroll
    for (int e = 0; e < 16; ++e) op[e] += scale * v[e];
  } else {
    float* dst = out + (size_t)idx * 2064;
#pragma unroll
    for (int e = 0; e < 16; ++e) dst[e] = scale * v[e];
  }
}

extern "C" void kernel_launch(void* const* d_in, const int* in_sizes, int n_in,
                              void* d_out, int out_size, void* d_ws, size_t ws_size,
                              hipStream_t stream) {
  const float* x = (const float*)d_in[0];   // [256,2048,8]
  const float* W = (const float*)d_in[1];   // [10,2048,16,8]
  float* out = (float*)d_out;               // [256,10,2064]
  float* ws = (float*)d_ws;

  // ws: part | oe | xh | wh
  const size_t part_f = (size_t)ICHUNKS * SJE;              // 5242880 floats
  const size_t xh_f   = (size_t)BB * II * 8 / 2;            // 2097152 float-equivalents
  const size_t wh_f   = (size_t)JJ * II * 128 / 2;          // 1310720
  const size_t need = (part_f + SJE + xh_f + wh_f) * sizeof(float); // ~34.8 MB

  if (ws_size >= need) {
    float* part = ws;
    float* oe   = ws + part_f;
    _Float16* xh = (_Float16*)(ws + part_f + SJE);
    _Float16* wh = (_Float16*)(ws + part_f + SJE + xh_f);
    prep_half<<<2048, 256, 0, stream>>>(x, W, xh, wh);
    pass0_mfma<<<dim3(32, 16), 256, 0, stream>>>(xh, wh, part);
    finish_pass<<<SJE / 256, 256, 0, stream>>>(part, oe, out, 0);
    routing_mfma<1><<<dim3(ICHUNKS, 16), 128, 0, stream>>>(xh, wh, oe, part, nullptr);
    finish_pass<<<SJE / 256, 256, 0, stream>>>(part, oe, out, 1);
    routing_mfma<2><<<dim3(ICHUNKS, 16), 128, 0, stream>>>(xh, wh, oe, part, out);
    finish_pass<<<SJE / 256, 256, 0, stream>>>(part, oe, out, 2);
  } else {
    float* s0 = ws;
    float* s1 = ws + SJE;
    float* s2 = ws + 2 * SJE;
    float* oe = ws + 3 * SJE;
    hipMemsetAsync(ws, 0, (size_t)4 * SJE * sizeof(float), stream);
    routing_pass_atomic<0><<<dim3(ICHUNKS, BB / BBLK), 256, 0, stream>>>(x, W, nullptr, s0, nullptr);
    squash_update<<<10, 256, 0, stream>>>(s0, oe, out, 0);
    routing_pass_atomic<1><<<dim3(ICHUNKS, BB / BBLK), 256, 0, stream>>>(x, W, oe, s1, nullptr);
    squash_update<<<10, 256, 0, stream>>>(s1, oe, out, 1);
    routing_pass_atomic<2><<<dim3(ICHUNKS, BB / BBLK), 256, 0, stream>>>(x, W, oe, s2, out);
    squash_update<<<10, 256, 0, stream>>>(s2, oe, out, 2);
  }
}

// Round 18
// 132.114 us; speedup vs baseline: 1.7552x; 1.0505x over previous
//
#include <hip/hip_runtime.h>
#include <math.h>

#define II 2048
#define BB 256
#define JJ 10
#define ICH 16            // i's per block
#define ICHUNKS (II/ICH)  // 128
#define SJE (BB*JJ*16)    // 40960
#define CPAD 20           // c_tile row stride (halves): banks spread, 8B-aligned

typedef __attribute__((address_space(3))) unsigned lds_u32;
typedef __attribute__((address_space(1))) const unsigned glb_u32;
typedef _Float16 h4 __attribute__((ext_vector_type(4)));
typedef _Float16 h8 __attribute__((ext_vector_type(8)));
typedef __attribute__((ext_vector_type(4))) float f32x4;

__device__ __forceinline__ void gload16(const void* g, void* l) {
  __builtin_amdgcn_global_load_lds((glb_u32*)g, (lds_u32*)l, 16, 0, 0);
}

// DPP row (16-lane) rotate: VALU-pipe cross-lane, no LDS traffic.
template<int N>
__device__ __forceinline__ float rrot16(float v) {
  const int i = __float_as_int(v);
  return __int_as_float(__builtin_amdgcn_update_dpp(i, i, 0x120 + N, 0xF, 0xF, false));
}
__device__ __forceinline__ float rsum16(float v) {
  v += rrot16<8>(v); v += rrot16<4>(v); v += rrot16<2>(v); v += rrot16<1>(v);
  return v;
}
__device__ __forceinline__ float xor16swz(float v) {  // lane ^ 16 (within 32-halves)
  return __int_as_float(__builtin_amdgcn_ds_swizzle(__float_as_int(v), 0x401F));
}

// -------- prep: fp32 -> f16 copies of x and W in ws --------
#define XF4 (BB * II * 8 / 4)        // 1048576 float4 slots
#define WF4 (JJ * II * 128 / 4)      // 655360
__global__ __launch_bounds__(256)
void prep_half(const float* __restrict__ x, const float* __restrict__ W,
               _Float16* __restrict__ xh, _Float16* __restrict__ wh) {
  for (int s = blockIdx.x * 256 + threadIdx.x; s < XF4 + WF4; s += gridDim.x * 256) {
    const float4 v = (s < XF4) ? *reinterpret_cast<const float4*>(x + (size_t)s * 4)
                               : *reinterpret_cast<const float4*>(W + (size_t)(s - XF4) * 4);
    h4 o; o.x = (_Float16)v.x; o.y = (_Float16)v.y; o.z = (_Float16)v.z; o.w = (_Float16)v.w;
    _Float16* dst = (s < XF4) ? (xh + (size_t)s * 4) : (wh + (size_t)(s - XF4) * 4);
    *reinterpret_cast<h4*>(dst) = o;
  }
}

// -------- PASS0 as f16 MFMA GEMM (s0 = x.W^T over (i,d); c==0.1 deferred) --------
__global__ __launch_bounds__(256)
void pass0_mfma(const _Float16* __restrict__ xh, const _Float16* __restrict__ wh,
                float* __restrict__ part) {
  const int t = threadIdx.x, wid = t >> 6, lane = t & 63;
  const int lg = lane >> 4, lm = lane & 15;
  const int chunk = blockIdx.x * 4 + wid;      // 0..127
  const int mb = blockIdx.y * 16;
  f32x4 acc0 = {0,0,0,0}, acc1 = {0,0,0,0}, acc2 = {0,0,0,0}, acc3 = {0,0,0,0};
  f32x4 acc4_ = {0,0,0,0}, acc5 = {0,0,0,0}, acc6 = {0,0,0,0}, acc7 = {0,0,0,0};
  f32x4 acc8 = {0,0,0,0}, acc9 = {0,0,0,0};
  const int ibase = chunk * 16;
#pragma unroll
  for (int ks = 0; ks < 4; ++ks) {
    const int i = ibase + ks * 4 + lg;
    const h8 a = *reinterpret_cast<const h8*>(xh + ((size_t)(mb + lm) * II + i) * 8);
#define MM(J, ACC)                                                              \
    {                                                                           \
      const h8 bv = *reinterpret_cast<const h8*>(                               \
          wh + (((size_t)(J) * II + i) * 16 + lm) * 8);                         \
      ACC = __builtin_amdgcn_mfma_f32_16x16x32_f16(a, bv, ACC, 0, 0, 0);        \
    }
    MM(0, acc0) MM(1, acc1) MM(2, acc2) MM(3, acc3) MM(4, acc4_)
    MM(5, acc5) MM(6, acc6) MM(7, acc7) MM(8, acc8) MM(9, acc9)
#undef MM
  }
  float* base = part + (size_t)chunk * SJE;
#define ST(J, ACC)                                                        \
  {                                                                       \
    _Pragma("unroll")                                                     \
    for (int r = 0; r < 4; ++r)                                           \
      base[((size_t)(mb + lg * 4 + r) * JJ + (J)) * 16 + lm] = ACC[r];    \
  }
  ST(0, acc0) ST(1, acc1) ST(2, acc2) ST(3, acc3) ST(4, acc4_)
  ST(5, acc5) ST(6, acc6) ST(7, acc7) ST(8, acc8) ST(9, acc9)
#undef ST
}

// -------- PASS1/2: swapped-operand MFMA routing, rolling W prefetch --------
// Per i, wave computes uh[e, b] for 16 b's via 10 MFMA (A=W_j rows=e,
// B=x cols=b; lanes>=16 zero). C: lane=(b=lm, eg), j in regs. Softmax over j
// register-local; e-reduce = xor16 + xor32 per j. Rolling prefetch: wf[j] is
// reloaded with i+1's fragment right after MFMA j consumes it -> next-i loads
// fly under this i's softmax (no per-j load stall).
template<int PASS>
__global__ __launch_bounds__(128, 1)
void routing_mfma(const _Float16* __restrict__ xh, const _Float16* __restrict__ wh,
                  const float* __restrict__ o_eff, float* __restrict__ part,
                  float* __restrict__ out) {
  __shared__ __align__(16) float s_acc[16 * 164];                   // 10.25 KB
  __shared__ _Float16 c_tile[(PASS == 2) ? (16 * JJ * CPAD) : 4];   // 6.25 KB (PASS2)

  const int t = threadIdx.x;
  const int w = t >> 6;                // wave 0/1
  const int lane = t & 63;
  const int lm = lane & 15;            // b-sub (MFMA col)
  const int eg = lane >> 4;            // e-group (MFMA row quad)
  const int ic = blockIdx.x;           // i-chunk (XCD = ic % 8)
  const int b0 = blockIdx.y * 16;
  const int b = b0 + lm;
  const int i0 = ic * ICH;

  // o[b, j, eg-slice], i-invariant
  float4 o[JJ];
#pragma unroll
  for (int j = 0; j < JJ; ++j)
    o[j] = *reinterpret_cast<const float4*>(
        o_eff + ((size_t)b * JJ + j) * 16 + eg * 4);

  f32x4 acc[JJ];
#pragma unroll
  for (int j = 0; j < JJ; ++j) acc[j] = f32x4{0.f, 0.f, 0.f, 0.f};

  const f32x4 z4 = {0.f, 0.f, 0.f, 0.f};
  h8 xfrag = {0, 0, 0, 0, 0, 0, 0, 0};   // lanes>=16 stay zero forever
  h8 wf[JJ];
#pragma unroll
  for (int j = 0; j < JJ; ++j) wf[j] = h8{0, 0, 0, 0, 0, 0, 0, 0};

  const _Float16* xrow = xh + (size_t)b * II * 8;
  const int ibeg = i0 + w * (ICH / 2);

  // prologue: load the first i's full batch
  if (lane < 16) {
    xfrag = *reinterpret_cast<const h8*>(xrow + (size_t)ibeg * 8);
#pragma unroll
    for (int j = 0; j < JJ; ++j)
      wf[j] = *reinterpret_cast<const h8*>(
          wh + (((size_t)j * II + ibeg) * 16 + lm) * 8);
  }

#pragma unroll 1
  for (int ii = 0; ii < ICH / 2; ++ii) {
    const int i = ibeg + ii;
    const int il = w * (ICH / 2) + ii;
    const int inext = (ii + 1 < ICH / 2) ? (i + 1) : i;   // clamp: safe redundant load

    f32x4 uh[JJ];
#pragma unroll
    for (int j = 0; j < JJ; ++j) {
      uh[j] = __builtin_amdgcn_mfma_f32_16x16x32_f16(wf[j], xfrag, z4, 0, 0, 0);
      if (lane < 16)        // rolling reload: frag j now holds i+1's data
        wf[j] = *reinterpret_cast<const h8*>(
            wh + (((size_t)j * II + inext) * 16 + lm) * 8);
    }
    if (lane < 16)          // x consumed by all 10 MFMAs; reload after last
      xfrag = *reinterpret_cast<const h8*>(xrow + (size_t)inext * 8);

    // logits: partial over this lane's 4 e's, then e-reduce across 4 groups
    float cj[JJ];
    float D = 0.f;
#pragma unroll
    for (int j = 0; j < JJ; ++j) {
      float v = o[j].x * uh[j][0];
      v = fmaf(o[j].y, uh[j][1], v);
      v = fmaf(o[j].z, uh[j][2], v);
      v = fmaf(o[j].w, uh[j][3], v);
      v += xor16swz(v);
      v += __shfl_xor(v, 32);
      const float pp = __expf(v);      // no max-sub: logits bounded, fp32 safe
      cj[j] = pp;
      D += pp;
    }
    const float rD = __builtin_amdgcn_rcpf(D);
#pragma unroll
    for (int j = 0; j < JJ; ++j) {
      const float c = cj[j] * rD;
      cj[j] = c;
      acc[j][0] = fmaf(c, uh[j][0], acc[j][0]);
      acc[j][1] = fmaf(c, uh[j][1], acc[j][1]);
      acc[j][2] = fmaf(c, uh[j][2], acc[j][2]);
      acc[j][3] = fmaf(c, uh[j][3], acc[j][3]);
    }
    if (PASS == 2) {
      // distribute c writes over eg groups: eg0->j0-2, eg1->j3-5, eg2->j6-8, eg3->j9
#pragma unroll
      for (int j = 0; j < JJ; ++j) {
        const int owner = (j >= 9) ? 3 : (j / 3);
        if (eg == owner)
          c_tile[(lm * JJ + j) * CPAD + il] = (_Float16)cj[j];
      }
    }
  }

  // combine the two waves' acc and store part
  if (w == 0) {
#pragma unroll
    for (int j = 0; j < JJ; ++j)
      *reinterpret_cast<f32x4*>(&s_acc[lm * 164 + j * 16 + eg * 4]) = acc[j];
  }
  __syncthreads();
  if (w == 1) {
#pragma unroll
    for (int j = 0; j < JJ; ++j) {
      f32x4 v = *reinterpret_cast<const f32x4*>(&s_acc[lm * 164 + j * 16 + eg * 4]);
      v += acc[j];
      *reinterpret_cast<f32x4*>(
          part + (size_t)ic * SJE + ((size_t)b * JJ + j) * 16 + eg * 4) = v;
    }
  }

  if (PASS == 2) {
    // coalesced c out: 160 rows x 16 i-floats
    for (int s = t; s < 16 * JJ * (ICH / 4); s += 128) {
      const int row = s >> 2, q = s & 3;
      const int bb = row / JJ, jj = row - bb * JJ;
      const h4 cv = *reinterpret_cast<const h4*>(&c_tile[row * CPAD + q * 4]);
      float4 ov;
      ov.x = (float)cv.x; ov.y = (float)cv.y; ov.z = (float)cv.z; ov.w = (float)cv.w;
      *reinterpret_cast<float4*>(
          out + ((size_t)(b0 + bb) * JJ + jj) * 2064 + 16 + i0 + q * 4) = ov;
    }
  }
}

// fused: reduce over 128 i-chunk partials + squash + output/o_eff update
__global__ __launch_bounds__(256)
void finish_pass(const float* __restrict__ part, float* __restrict__ o_eff,
                 float* __restrict__ out, int pass) {
  const int idx = blockIdx.x * 256 + threadIdx.x;
  float a = 0.f;
#pragma unroll 8
  for (int k = 0; k < ICHUNKS; ++k) a += part[(size_t)k * SJE + idx];
  if (pass == 0) a *= 0.1f;
  const float s2 = rsum16(a * a);
  const float scale = s2 / ((1.f + s2) * sqrtf(s2 + 1e-7f));
  const float v = scale * a;
  if (pass == 0) o_eff[idx] = v;
  else if (pass == 1) o_eff[idx] += v;
  else out[(size_t)(idx >> 4) * 2064 + (idx & 15)] = v;
}

// -------- fp32 atomic fallback (round-13-proven), used only if ws too small --------
#define BBLK 32
#define NBW 8
template<int PASS>
__global__ __launch_bounds__(256, 1)
void routing_pass_atomic(const float* __restrict__ x, const float* __restrict__ W,
                         const float* __restrict__ o_eff, float* __restrict__ sdst,
                         float* __restrict__ out) {
  __shared__ __align__(16) float x_lds[BBLK * ICH * 8];
  __shared__ _Float16 c_tile[(PASS == 2) ? (BBLK * JJ * 18) : 4];

  const int t = threadIdx.x;
  const int wid = t >> 6;
  const int lane = t & 63;
  const int eg = lane >> 4;
  const int j = lane & 15;
  const int jv = (j < JJ);
  const int jr = jv ? j : 0;
  const int ic = blockIdx.x;
  const int b0 = blockIdx.y * BBLK;
  const int bw = __builtin_amdgcn_readfirstlane(b0 + wid * NBW);
  const int i0 = ic * ICH;
  const float* wbase = W + ((size_t)jr * II + i0) * 128 + eg * 32;

  float4 o4[NBW];
  if (PASS > 0) {
#pragma unroll
    for (int nb = 0; nb < NBW; ++nb)
      o4[nb] = *reinterpret_cast<const float4*>(
          o_eff + ((size_t)(bw + nb) * JJ + jr) * 16 + eg * 4);
  }
  float4 acc4[NBW];
#pragma unroll
  for (int nb = 0; nb < NBW; ++nb) acc4[nb] = make_float4(0.f, 0.f, 0.f, 0.f);

#pragma unroll
  for (int k = 0; k < 4; ++k) {
    const int s = k * 256 + t;
    const int bl = s >> 5, rem = s & 31, il = rem >> 1, h = rem & 1;
    gload16(x + ((size_t)(b0 + bl) * II + i0 + il) * 8 + h * 4,
            &x_lds[(k * 256 + wid * 64) * 4]);
  }
  __syncthreads();

#pragma unroll 1
  for (int il = 0; il < ICH; ++il) {
    const float* wp = wbase + il * 128;
    float4 wv[8];
#pragma unroll
    for (int r = 0; r < 8; ++r)
      wv[r] = *reinterpret_cast<const float4*>(wp + r * 4);
#pragma unroll
    for (int nb = 0; nb < NBW; ++nb) {
      const float* xp = &x_lds[((wid * NBW + nb) * ICH + il) * 8];
      const float4 xa = *reinterpret_cast<const float4*>(xp);
      const float4 xb = *reinterpret_cast<const float4*>(xp + 4);
#define DOT8F(q, dst)                                  \
      float dst = wv[2*(q)].x * xa.x;                  \
      dst = fmaf(wv[2*(q)].y, xa.y, dst);              \
      dst = fmaf(wv[2*(q)].z, xa.z, dst);              \
      dst = fmaf(wv[2*(q)].w, xa.w, dst);              \
      dst = fmaf(wv[2*(q)+1].x, xb.x, dst);            \
      dst = fmaf(wv[2*(q)+1].y, xb.y, dst);            \
      dst = fmaf(wv[2*(q)+1].z, xb.z, dst);            \
      dst = fmaf(wv[2*(q)+1].w, xb.w, dst);
      DOT8F(0, u0) DOT8F(1, u1) DOT8F(2, u2) DOT8F(3, u3)
#undef DOT8F
      float c;
      if (PASS == 0) {
        c = 0.1f;
      } else {
        float lp = o4[nb].x * u0;
        lp = fmaf(o4[nb].y, u1, lp);
        lp = fmaf(o4[nb].z, u2, lp);
        lp = fmaf(o4[nb].w, u3, lp);
        lp += xor16swz(lp);
        lp += __shfl_xor(lp, 32);
        const float pp = jv ? __expf(lp) : 0.f;
        const float su = rsum16(pp);
        c = pp * __builtin_amdgcn_rcpf(su);
      }
      acc4[nb].x = fmaf(c, u0, acc4[nb].x);
      acc4[nb].y = fmaf(c, u1, acc4[nb].y);
      acc4[nb].z = fmaf(c, u2, acc4[nb].z);
      acc4[nb].w = fmaf(c, u3, acc4[nb].w);
      if (PASS == 2) {
        if (eg == 0 && jv)
          c_tile[((wid * NBW + nb) * JJ + j) * 18 + il] = (_Float16)c;
      }
    }
  }

  if (PASS == 2) {
    __syncthreads();
    for (int s = t; s < BBLK * JJ * ICH; s += 256) {
      const int row = s >> 4, col = s & 15;
      const int bb = row / 10, jj = row - bb * 10;
      out[((size_t)(b0 + bb) * JJ + jj) * 2064 + 16 + i0 + col] =
          (float)c_tile[row * 18 + col];
    }
  }

  if (jv) {
#pragma unroll
    for (int nb = 0; nb < NBW; ++nb) {
      float* sp = sdst + ((size_t)(bw + nb) * JJ + j) * 16 + eg * 4;
      atomicAdd(&sp[0], acc4[nb].x);
      atomicAdd(&sp[1], acc4[nb].y);
      atomicAdd(&sp[2], acc4[nb].z);
      atomicAdd(&sp[3], acc4[nb].w);
    }
  }
}

__global__ __launch_bounds__(256)
void squash_update(const float* __restrict__ s, float* __restrict__ o_eff,
                   float* __restrict__ out, int pass) {
  const int idx = blockIdx.x * blockDim.x + threadIdx.x;
  if (idx >= BB * JJ) return;
  const float* sp = s + (size_t)idx * 16;
  const float pre = (pass == 0) ? 0.1f : 1.f;
  float v[16];
  float s2 = 0.f;
#pragma unroll
  for (int e = 0; e < 16; ++e) { v[e] = pre * sp[e]; s2 = fmaf(v[e], v[e], s2); }
  const float scale = s2 / ((1.f + s2) * sqrtf(s2 + 1e-7f));
  if (pass == 0) {
    float* op = o_eff + (size_t)idx * 16;
#pragma unroll
    for (int e = 0; e < 16; ++e) op[e] = scale * v[e];
  } else if (pass == 1) {
    float* op = o_eff + (size_t)idx * 16;
#pragma unroll
    for (int e = 0; e < 16; ++e) op[e] += scale * v[e];
  } else {
    float* dst = out + (size_t)idx * 2064;
#pragma unroll
    for (int e = 0; e < 16; ++e) dst[e] = scale * v[e];
  }
}

extern "C" void kernel_launch(void* const* d_in, const int* in_sizes, int n_in,
                              void* d_out, int out_size, void* d_ws, size_t ws_size,
                              hipStream_t stream) {
  const float* x = (const float*)d_in[0];   // [256,2048,8]
  const float* W = (const float*)d_in[1];   // [10,2048,16,8]
  float* out = (float*)d_out;               // [256,10,2064]
  float* ws = (float*)d_ws;

  // ws: part | oe | xh | wh
  const size_t part_f = (size_t)ICHUNKS * SJE;              // 5242880 floats
  const size_t xh_f   = (size_t)BB * II * 8 / 2;            // 2097152 float-equivalents
  const size_t wh_f   = (size_t)JJ * II * 128 / 2;          // 1310720
  const size_t need = (part_f + SJE + xh_f + wh_f) * sizeof(float); // ~34.8 MB

  if (ws_size >= need) {
    float* part = ws;
    float* oe   = ws + part_f;
    _Float16* xh = (_Float16*)(ws + part_f + SJE);
    _Float16* wh = (_Float16*)(ws + part_f + SJE + xh_f);
    prep_half<<<2048, 256, 0, stream>>>(x, W, xh, wh);
    pass0_mfma<<<dim3(32, 16), 256, 0, stream>>>(xh, wh, part);
    finish_pass<<<SJE / 256, 256, 0, stream>>>(part, oe, out, 0);
    routing_mfma<1><<<dim3(ICHUNKS, 16), 128, 0, stream>>>(xh, wh, oe, part, nullptr);
    finish_pass<<<SJE / 256, 256, 0, stream>>>(part, oe, out, 1);
    routing_mfma<2><<<dim3(ICHUNKS, 16), 128, 0, stream>>>(xh, wh, oe, part, out);
    finish_pass<<<SJE / 256, 256, 0, stream>>>(part, oe, out, 2);
  } else {
    float* s0 = ws;
    float* s1 = ws + SJE;
    float* s2 = ws + 2 * SJE;
    float* oe = ws + 3 * SJE;
    hipMemsetAsync(ws, 0, (size_t)4 * SJE * sizeof(float), stream);
    routing_pass_atomic<0><<<dim3(ICHUNKS, BB / BBLK), 256, 0, stream>>>(x, W, nullptr, s0, nullptr);
    squash_update<<<10, 256, 0, stream>>>(s0, oe, out, 0);
    routing_pass_atomic<1><<<dim3(ICHUNKS, BB / BBLK), 256, 0, stream>>>(x, W, oe, s1, nullptr);
    squash_update<<<10, 256, 0, stream>>>(s1, oe, out, 1);
    routing_pass_atomic<2><<<dim3(ICHUNKS, BB / BBLK), 256, 0, stream>>>(x, W, oe, s2, out);
    squash_update<<<10, 256, 0, stream>>>(s2, oe, out, 2);
  }
}